// Round 13
// baseline (461.205 us; speedup 1.0000x reference)
//
#include <hip/hip_runtime.h>
#include <hip/hip_bf16.h>

#define BN_EPS 1e-5f
#define NBMAX 512      // max buckets (N/256)
#define CHUNK 4096     // edges per binning block
#define CAP   5120     // fixed per-bucket capacity (mean 4096 + 16 sigma)
#define CAPC  6144     // per-bucket LDS staging capacity

typedef __hip_bfloat16 bf16;
typedef __attribute__((ext_vector_type(8))) short short8;
typedef __attribute__((ext_vector_type(4))) float f32x4;

__device__ __forceinline__ float b2f(bf16 v) { return __bfloat162float(v); }
__device__ __forceinline__ bf16 f2b(float v) { return __float2bfloat16(v); }
__device__ __forceinline__ float bl(unsigned u) { return __uint_as_float(u << 16); }
__device__ __forceinline__ float bh(unsigned u) { return __uint_as_float(u & 0xffff0000u); }
__device__ __forceinline__ unsigned pack2(float x, float y) {
    union { bf16 b[2]; unsigned u; } p;
    p.b[0] = f2b(x); p.b[1] = f2b(y);
    return p.u;
}
__device__ __forceinline__ float bs2f(short s) {
    return __uint_as_float(((unsigned)(unsigned short)s) << 16);
}
__device__ __forceinline__ short f2bs(float v) {
    bf16 b = f2b(v);
    return *reinterpret_cast<short*>(&b);
}

// ============ init bcur (fixed-stride bases) + ctrs + cast x -> bf16 ============
__global__ __launch_bounds__(256) void initcast_k(
    const float* __restrict__ in, bf16* __restrict__ out, int total4,
    int* __restrict__ bcur, int NB, unsigned* __restrict__ ctrs)
{
    if (blockIdx.x == 0) {
        for (int i = threadIdx.x; i < NB; i += 256) bcur[i] = i * CAP;
        if (threadIdx.x < 4) ctrs[threadIdx.x] = 0u;
    }
    int i = blockIdx.x * 256 + threadIdx.x;
    if (i >= total4) return;
    float4 v = ((const float4*)in)[i];
    union { ushort4 u; bf16 b[4]; } p;
    p.b[0] = f2b(v.x); p.b[1] = f2b(v.y); p.b[2] = f2b(v.z); p.b[3] = f2b(v.w);
    ((ushort4*)out)[i] = p.u;
}

// ============ binscatter: group edges by bucket in LDS, write runs ============
__global__ __launch_bounds__(256) void binscatter_k(
    const int* __restrict__ src, const int* __restrict__ dst,
    int* __restrict__ bcur, int* __restrict__ tmp, int E, int NB)
{
    __shared__ int hist[NBMAX];
    __shared__ int loff[NBMAX];
    __shared__ int gb[NBMAX];
    __shared__ int lcur[NBMAX];
    __shared__ int staged[CHUNK];
    __shared__ unsigned short sb[CHUNK];
    __shared__ int ssc[256];
    const int t = threadIdx.x;
    for (int i = t; i < NB; i += 256) { hist[i] = 0; lcur[i] = 0; }
    __syncthreads();
    const int base = blockIdx.x * CHUNK;
    const int lim = min(CHUNK, E - base);
    int myb[16], myw[16];
    int cnt = 0;
    for (int i = t; i < lim; i += 256) {
        int d = dst[base + i];
        int s_ = src[base + i];
        int b = d >> 8;
        myb[cnt] = b;
        myw[cnt] = (s_ << 8) | (d & 255);
        cnt++;
        atomicAdd(&hist[b], 1);
    }
    __syncthreads();
    int v0 = (2 * t     < NB) ? hist[2 * t]     : 0;
    int v1 = (2 * t + 1 < NB) ? hist[2 * t + 1] : 0;
    ssc[t] = v0 + v1;
    __syncthreads();
    for (int off = 1; off < 256; off <<= 1) {
        int a = (t >= off) ? ssc[t - off] : 0;
        __syncthreads();
        ssc[t] += a;
        __syncthreads();
    }
    int excl = ssc[t] - (v0 + v1);
    if (2 * t < NB)     loff[2 * t] = excl;
    if (2 * t + 1 < NB) loff[2 * t + 1] = excl + v0;
    __syncthreads();
    for (int b = t; b < NB; b += 256)
        if (hist[b] > 0) gb[b] = atomicAdd(&bcur[b], hist[b]);
    for (int i = 0; i < cnt; i++) {
        int b = myb[i];
        int p = loff[b] + atomicAdd(&lcur[b], 1);
        staged[p] = myw[i];
        sb[p] = (unsigned short)b;
    }
    __syncthreads();
    for (int i = t; i < lim; i += 256) {
        int b = sb[i];
        tmp[gb[b] + (i - loff[b])] = staged[i];
    }
}

// ============ csr: per bucket counting sort -> rowptr/rowend + adj ============
__global__ __launch_bounds__(256) void csr_k(
    const int* __restrict__ bcur, const int* __restrict__ tmp,
    int* __restrict__ rowptr, int* __restrict__ rowend,
    int* __restrict__ adj, int N)
{
    __shared__ int hist[256], pfx[256], cur[256], ssc[256];
    __shared__ int sadj[CAPC];
    const int b = blockIdx.x, t = threadIdx.x;
    const int lo = b * CAP;
    const int cnt = min(bcur[b] - lo, CAP);
    hist[t] = 0; cur[t] = 0;
    __syncthreads();
    for (int i = t; i < cnt; i += 256)
        atomicAdd(&hist[tmp[lo + i] & 255], 1);
    __syncthreads();
    int v = hist[t];
    ssc[t] = v;
    __syncthreads();
    for (int off = 1; off < 256; off <<= 1) {
        int a = (t >= off) ? ssc[t - off] : 0;
        __syncthreads();
        ssc[t] += a;
        __syncthreads();
    }
    pfx[t] = ssc[t] - v;
    const int node = b * 256 + t;
    if (node < N) {
        rowptr[node] = lo + pfx[t];
        rowend[node] = lo + pfx[t] + v;
    }
    __syncthreads();
    if (cnt <= CAPC) {
        for (int i = t; i < cnt; i += 256) {
            int w = tmp[lo + i];
            int d = w & 255;
            int p = pfx[d] + atomicAdd(&cur[d], 1);
            sadj[p] = w >> 8;
        }
        __syncthreads();
        for (int i = t; i < cnt; i += 256) adj[lo + i] = sadj[i];
    } else {
        for (int i = t; i < cnt; i += 256) {
            int w = tmp[lo + i];
            int d = w & 255;
            int p = pfx[d] + atomicAdd(&cur[d], 1);
            adj[lo + p] = w >> 8;
        }
    }
}

// ========== aggregation: z[n] = act(h[n]) + sum_m act(h[m]) ==========
// half-wave per node: lane carries feature pair via 4B load; unroll 16.
// AFFINE=1: act(v) = relu(v*sc+sh), sc/sh precomputed by gemm epilogue.
template<int AFFINE>
__global__ __launch_bounds__(256) void aggregate_k(
    const bf16* __restrict__ h, const int* __restrict__ rowptr,
    const int* __restrict__ rowend, const int* __restrict__ adj,
    bf16* __restrict__ z, int N,
    const float* __restrict__ sc, const float* __restrict__ sh)
{
    const int lane = threadIdx.x & 31;
    const int n = blockIdx.x * 8 + (threadIdx.x >> 5);
    float sc0 = 0.f, sc1 = 0.f, sh0 = 0.f, sh1 = 0.f;
    if (AFFINE) {
        const int f0 = lane * 2;
        sc0 = sc[f0]; sc1 = sc[f0 + 1];
        sh0 = sh[f0]; sh1 = sh[f0 + 1];
    }
    if (n >= N) return;
    const unsigned* hp = (const unsigned*)h;   // bf16x2 words, row stride 32
    const int b = rowptr[n], e = rowend[n];

    unsigned u = hp[(size_t)n * 32 + lane];
    float a0 = bl(u), a1 = bh(u);
    if (AFFINE) {
        a0 = fmaxf(fmaf(a0, sc0, sh0), 0.f);
        a1 = fmaxf(fmaf(a1, sc1, sh1), 0.f);
    }
    float s0 = a0, s1 = a1;

    int i = b;
    for (; i + 16 <= e; i += 16) {
        int m[16];
        #pragma unroll
        for (int k = 0; k < 16; k++) m[k] = adj[i + k];
        unsigned w[16];
        #pragma unroll
        for (int k = 0; k < 16; k++) w[k] = hp[(size_t)m[k] * 32 + lane];
        #pragma unroll
        for (int k = 0; k < 16; k++) {
            float p0 = bl(w[k]), p1 = bh(w[k]);
            if (AFFINE) {
                p0 = fmaxf(fmaf(p0, sc0, sh0), 0.f);
                p1 = fmaxf(fmaf(p1, sc1, sh1), 0.f);
            }
            s0 += p0; s1 += p1;
        }
    }
    for (; i + 4 <= e; i += 4) {
        int m[4];
        #pragma unroll
        for (int k = 0; k < 4; k++) m[k] = adj[i + k];
        #pragma unroll
        for (int k = 0; k < 4; k++) {
            unsigned w = hp[(size_t)m[k] * 32 + lane];
            float p0 = bl(w), p1 = bh(w);
            if (AFFINE) {
                p0 = fmaxf(fmaf(p0, sc0, sh0), 0.f);
                p1 = fmaxf(fmaf(p1, sc1, sh1), 0.f);
            }
            s0 += p0; s1 += p1;
        }
    }
    for (; i < e; i++) {
        unsigned w = hp[(size_t)adj[i] * 32 + lane];
        float p0 = bl(w), p1 = bh(w);
        if (AFFINE) {
            p0 = fmaxf(fmaf(p0, sc0, sh0), 0.f);
            p1 = fmaxf(fmaf(p1, sc1, sh1), 0.f);
        }
        s0 += p0; s1 += p1;
    }
    ((unsigned*)z)[(size_t)n * 32 + lane] = pack2(s0, s1);
}

// ---------------- MFMA GEMM (bf16 in/out, f32 acc) + fused BN finalize ----------------
// C[N x 64] = act(A) @ W + bias.  MODE 0: act = id;  MODE 1: act = relu(A*sc+sh).
// Per-block stats -> pstat (no atomics). Ticket epilogue: the last 64 blocks
// to finish spin until all pstat written, then reduce one feature each ->
// scout/shout (deadlock-free: spinners already ran; others never block).
template<int MODE>
__global__ __launch_bounds__(256) void gemm64_k(
    const bf16* __restrict__ A,
    const float* __restrict__ scin, const float* __restrict__ shin,
    const float* __restrict__ W, const float* __restrict__ bias,
    bf16* __restrict__ out, float* __restrict__ pstat, int nrows,
    unsigned* __restrict__ ctr, int PG,
    const float* __restrict__ g, const float* __restrict__ be, float invN,
    float* __restrict__ scout, float* __restrict__ shout)
{
    __shared__ bf16 sWt[64][72];     // transposed W (n-major)
    __shared__ float sSc[64], sSh[64], sB[64];
    __shared__ float sredS[64][17], sredQ[64][17];
    __shared__ unsigned sTicket;
    const int tid = threadIdx.x;

    if (tid < 64) {
        sB[tid] = bias[tid];
        if (MODE == 1) { sSc[tid] = scin[tid]; sSh[tid] = shin[tid]; }
    }
    for (int i = tid; i < 4096; i += 256) {
        int k = i >> 6, n = i & 63;
        sWt[n][k] = f2b(W[i]);
    }
    __syncthreads();

    const int wave = tid >> 6, lane = tid & 63;
    const int quad = lane >> 4, l16 = lane & 15;
    const int row0 = blockIdx.x * 128 + wave * 32;

    short8 a[2][2];
    #pragma unroll
    for (int rt = 0; rt < 2; rt++) {
        int r = row0 + rt * 16 + l16;
        int rr = min(r, nrows - 1);
        const bf16* arow = A + (size_t)rr * 64;
        a[rt][0] = *(const short8*)(arow + quad * 8);
        a[rt][1] = *(const short8*)(arow + 32 + quad * 8);
        if (MODE == 1) {
            #pragma unroll
            for (int j = 0; j < 8; j++) {
                int f0 = quad * 8 + j;
                a[rt][0][j] = f2bs(fmaxf(fmaf(bs2f(a[rt][0][j]), sSc[f0], sSh[f0]), 0.f));
                int f1 = 32 + f0;
                a[rt][1][j] = f2bs(fmaxf(fmaf(bs2f(a[rt][1][j]), sSc[f1], sSh[f1]), 0.f));
            }
        }
    }

    float psS[4], psQ[4];
    #pragma unroll
    for (int t = 0; t < 4; t++) { psS[t] = 0.f; psQ[t] = 0.f; }

    #pragma unroll
    for (int t = 0; t < 4; t++) {
        const int n = t * 16 + l16;
        short8 b0 = *(const short8*)&sWt[n][quad * 8];
        short8 b1 = *(const short8*)&sWt[n][32 + quad * 8];
        const float bn_ = sB[n];
        #pragma unroll
        for (int rt = 0; rt < 2; rt++) {
            f32x4 acc = {0.f, 0.f, 0.f, 0.f};
            acc = __builtin_amdgcn_mfma_f32_16x16x32_bf16(a[rt][0], b0, acc, 0, 0, 0);
            acc = __builtin_amdgcn_mfma_f32_16x16x32_bf16(a[rt][1], b1, acc, 0, 0, 0);
            #pragma unroll
            for (int reg = 0; reg < 4; reg++) {
                int gr = row0 + rt * 16 + quad * 4 + reg;
                if (gr < nrows) {
                    float v = acc[reg] + bn_;
                    out[(size_t)gr * 64 + n] = f2b(v);
                    psS[t] += v;
                    psQ[t] = fmaf(v, v, psQ[t]);
                }
            }
        }
    }

    #pragma unroll
    for (int t = 0; t < 4; t++) {
        sredS[t * 16 + l16][wave * 4 + quad] = psS[t];
        sredQ[t * 16 + l16][wave * 4 + quad] = psQ[t];
    }
    __syncthreads();
    if (tid < 128) {
        const int c = tid & 63;
        const float* p = (tid < 64) ? &sredS[c][0] : &sredQ[c][0];
        float s = 0.f;
        #pragma unroll
        for (int i = 0; i < 16; i++) s += p[i];
        pstat[(size_t)blockIdx.x * 128 + (tid < 64 ? c : 64 + c)] = s;
    }

    // ---- ticket epilogue: last 64 finishers reduce pstat -> sc/sh ----
    __syncthreads();                  // all pstat stores drained (vmcnt per thread)
    if (tid == 0) {
        __threadfence();              // release: L2 writeback to device scope
        sTicket = atomicAdd(ctr, 1u);
    }
    __syncthreads();
    const int ticket = (int)sTicket;
    if (ticket >= PG - 64) {
        if (tid == 0) {
            while (atomicAdd(ctr, 0u) < (unsigned)PG) __builtin_amdgcn_s_sleep(2);
        }
        __syncthreads();
        __threadfence();              // acquire: invalidate stale L2 lines
        const int f = ticket - (PG - 64);   // 0..63
        float S = 0.f, Q = 0.f;
        for (int b = tid; b < PG; b += 256) {
            S += pstat[(size_t)b * 128 + f];
            Q += pstat[(size_t)b * 128 + 64 + f];
        }
        float* rs = &sredS[0][0];
        float* rq = &sredQ[0][0];
        rs[tid] = S; rq[tid] = Q;
        __syncthreads();
        for (int off = 128; off > 0; off >>= 1) {
            if (tid < off) { rs[tid] += rs[tid + off]; rq[tid] += rq[tid + off]; }
            __syncthreads();
        }
        if (tid == 0) {
            float m = rs[0] * invN;
            float v = rq[0] * invN - m * m;
            float s = g[f] * rsqrtf(v + BN_EPS);
            scout[f] = s;
            shout[f] = be[f] - m * s;
        }
    }
}

// ---------------- pooled readout; h1/h2 affine+relu applied on the fly ----------------
__global__ __launch_bounds__(256) void pool_readout_k(
    const bf16* __restrict__ xb, const bf16* __restrict__ z0,
    const bf16* __restrict__ z1, const int* __restrict__ batch,
    const float* __restrict__ scA, const float* __restrict__ shA,
    const float* __restrict__ scB, const float* __restrict__ shB,
    const float* __restrict__ w0, const float* __restrict__ b0,
    const float* __restrict__ w1, const float* __restrict__ b1,
    const float* __restrict__ w2, const float* __restrict__ b2,
    float* __restrict__ out, int Nn)
{
    const int g = blockIdx.x;
    int lo = 0, hi = Nn;
    while (lo < hi) { int mid = (lo + hi) >> 1; if (batch[mid] < g) lo = mid + 1; else hi = mid; }
    const int start = lo;
    hi = Nn;
    while (lo < hi) { int mid = (lo + hi) >> 1; if (batch[mid] <= g) lo = mid + 1; else hi = mid; }
    const int end = lo;

    const int f = threadIdx.x & 63;
    const int w = threadIdx.x >> 6;
    const float sA = scA[f], tA = shA[f];
    const float sB = scB[f], tB = shB[f];

    float s0 = 0.f, s1 = 0.f, s2 = 0.f;
    for (int i = start + w; i < end; i += 4) {
        s0 += b2f(xb[(size_t)i * 64 + f]);
        s1 += fmaxf(fmaf(b2f(z0[(size_t)i * 64 + f]), sA, tA), 0.f);
        s2 += fmaxf(fmaf(b2f(z1[(size_t)i * 64 + f]), sB, tB), 0.f);
    }
    __shared__ float p[3][4][64];
    p[0][w][f] = s0; p[1][w][f] = s1; p[2][w][f] = s2;
    __syncthreads();
    if (threadIdx.x < 10) {
        const int c = threadIdx.x;
        float acc = b0[c] + b1[c] + b2[c];
        for (int k = 0; k < 64; k++) {
            float q0 = p[0][0][k] + p[0][1][k] + p[0][2][k] + p[0][3][k];
            float q1 = p[1][0][k] + p[1][1][k] + p[1][2][k] + p[1][3][k];
            float q2 = p[2][0][k] + p[2][1][k] + p[2][2][k] + p[2][3][k];
            acc = fmaf(q0, w0[k * 10 + c], acc);
            acc = fmaf(q1, w1[k * 10 + c], acc);
            acc = fmaf(q2, w2[k * 10 + c], acc);
        }
        out[(size_t)g * 10 + c] = acc;
    }
}

extern "C" void kernel_launch(void* const* d_in, const int* in_sizes, int n_in,
                              void* d_out, int out_size, void* d_ws, size_t ws_size,
                              hipStream_t stream)
{
    const float* x     = (const float*)d_in[0];
    const int*   edge  = (const int*)d_in[1];
    const int*   batch = (const int*)d_in[2];
    const int N = in_sizes[0] / 64;
    const int E = in_sizes[1] / 2;
    const int G = out_size / 10;
    const int* src = edge;
    const int* dst = edge + E;
    const int NB = (N + 255) / 256;

    const float* c_w1[2]  = {(const float*)d_in[3],  (const float*)d_in[11]};
    const float* c_b1[2]  = {(const float*)d_in[4],  (const float*)d_in[12]};
    const float* c_g1[2]  = {(const float*)d_in[5],  (const float*)d_in[13]};
    const float* c_be1[2] = {(const float*)d_in[6],  (const float*)d_in[14]};
    const float* c_w2[2]  = {(const float*)d_in[7],  (const float*)d_in[15]};
    const float* c_b2[2]  = {(const float*)d_in[8],  (const float*)d_in[16]};
    const float* bn_g[2]  = {(const float*)d_in[9],  (const float*)d_in[17]};
    const float* bn_b[2]  = {(const float*)d_in[10], (const float*)d_in[18]};
    const float* lw[3]    = {(const float*)d_in[19], (const float*)d_in[21], (const float*)d_in[23]};
    const float* lb[3]    = {(const float*)d_in[20], (const float*)d_in[22], (const float*)d_in[24]};

    float* out = (float*)d_out;
    const size_t nh = (size_t)N * 64;
    const int PG = (N + 127) / 128;   // gemm grid

    // workspace layout
    bf16*  zb    = (bf16*)d_ws;                // nh bf16 (L0 t/y buffer)
    bf16*  wb    = zb + nh;                    // nh bf16 (L1 t/y buffer)
    bf16*  xb    = wb + nh;                    // nh bf16
    float* scsh  = (float*)(xb + nh);          // 8 x 64
    float* pstat = scsh + 512;                 // PG x 128
    int*   rowptr = (int*)(pstat + (size_t)PG * 128);  // N
    int*   rowend = rowptr + N;                // N
    int*   adj    = rowend + N;                // NB*CAP
    int*   tmp    = adj + (size_t)NB * CAP;    // NB*CAP
    int*   bcur   = tmp + (size_t)NB * CAP;    // NB
    unsigned* ctrs = (unsigned*)(bcur + NB);   // 4

    float* sc0 = scsh;       float* sh0 = scsh + 64;
    float* scA = scsh + 128; float* shA = scsh + 192;
    float* sc2 = scsh + 256; float* sh2 = scsh + 320;
    float* scB = scsh + 384; float* shB = scsh + 448;

    const float invN = 1.0f / (float)N;
    const int binGrid  = (E + CHUNK - 1) / CHUNK;
    const int aggGrid  = (N + 7) / 8;
    const int ewGrid   = (int)((nh / 4 + 255) / 256);

    // ---- init+cast, CSR build (fixed-stride buckets) ----
    initcast_k<<<ewGrid, 256, 0, stream>>>(x, xb, (int)(nh / 4), bcur, NB, ctrs);
    binscatter_k<<<binGrid, 256, 0, stream>>>(src, dst, bcur, tmp, E, NB);
    csr_k<<<NB, 256, 0, stream>>>(bcur, tmp, rowptr, rowend, adj, N);

    // ---- layer 0 ----
    aggregate_k<0><<<aggGrid, 256, 0, stream>>>(xb, rowptr, rowend, adj, zb, N,
                                                nullptr, nullptr);
    gemm64_k<0><<<PG, 256, 0, stream>>>(zb, nullptr, nullptr,
                                        c_w1[0], c_b1[0], zb, pstat, N,
                                        ctrs + 0, PG, c_g1[0], c_be1[0], invN, sc0, sh0);
    gemm64_k<1><<<PG, 256, 0, stream>>>(zb, sc0, sh0,
                                        c_w2[0], c_b2[0], zb, pstat, N,
                                        ctrs + 1, PG, bn_g[0], bn_b[0], invN, scA, shA);

    // ---- layer 1 (h1 = relu(affine(y0)) applied inside aggregate) ----
    aggregate_k<1><<<aggGrid, 256, 0, stream>>>(zb, rowptr, rowend, adj, wb, N,
                                                scA, shA);
    gemm64_k<0><<<PG, 256, 0, stream>>>(wb, nullptr, nullptr,
                                        c_w1[1], c_b1[1], wb, pstat, N,
                                        ctrs + 2, PG, c_g1[1], c_be1[1], invN, sc2, sh2);
    gemm64_k<1><<<PG, 256, 0, stream>>>(wb, sc2, sh2,
                                        c_w2[1], c_b2[1], wb, pstat, N,
                                        ctrs + 3, PG, bn_g[1], bn_b[1], invN, scB, shB);

    // ---- pooled readout (h1/h2 affine+relu fused) ----
    pool_readout_k<<<G, 256, 0, stream>>>(xb, zb, wb, batch,
                                          scA, shA, scB, shB,
                                          lw[0], lb[0], lw[1], lb[1], lw[2], lb[2],
                                          out, N);
}

// Round 14
// 314.871 us; speedup vs baseline: 1.4647x; 1.4647x over previous
//
#include <hip/hip_runtime.h>
#include <hip/hip_bf16.h>

#define BN_EPS 1e-5f
#define NBMAX 512      // max buckets (N/256)
#define CHUNK 4096     // edges per binning block
#define CAP   5120     // fixed per-bucket capacity (mean 4096 + 16 sigma)
#define CAPC  6144     // per-bucket LDS staging capacity

typedef __hip_bfloat16 bf16;
typedef __attribute__((ext_vector_type(8))) short short8;
typedef __attribute__((ext_vector_type(4))) float f32x4;

__device__ __forceinline__ float b2f(bf16 v) { return __bfloat162float(v); }
__device__ __forceinline__ bf16 f2b(float v) { return __float2bfloat16(v); }
__device__ __forceinline__ float bl(unsigned u) { return __uint_as_float(u << 16); }
__device__ __forceinline__ float bh(unsigned u) { return __uint_as_float(u & 0xffff0000u); }
__device__ __forceinline__ unsigned pack2(float x, float y) {
    union { bf16 b[2]; unsigned u; } p;
    p.b[0] = f2b(x); p.b[1] = f2b(y);
    return p.u;
}
__device__ __forceinline__ float bs2f(short s) {
    return __uint_as_float(((unsigned)(unsigned short)s) << 16);
}
__device__ __forceinline__ short f2bs(float v) {
    bf16 b = f2b(v);
    return *reinterpret_cast<short*>(&b);
}

// ============ init bcur (fixed-stride bases) + cast x -> bf16 ============
__global__ __launch_bounds__(256) void initcast_k(
    const float* __restrict__ in, bf16* __restrict__ out, int total4,
    int* __restrict__ bcur, int NB)
{
    if (blockIdx.x == 0) {
        for (int i = threadIdx.x; i < NB; i += 256) bcur[i] = i * CAP;
    }
    int i = blockIdx.x * 256 + threadIdx.x;
    if (i >= total4) return;
    float4 v = ((const float4*)in)[i];
    union { ushort4 u; bf16 b[4]; } p;
    p.b[0] = f2b(v.x); p.b[1] = f2b(v.y); p.b[2] = f2b(v.z); p.b[3] = f2b(v.w);
    ((ushort4*)out)[i] = p.u;
}

// ============ binscatter: ranked direct scatter into fixed-stride buckets ====
// pass 1: per-edge rank within (block, bucket) from the histogram atomic;
// reserve per-bucket global ranges; 16 independent direct stores. No scans,
// no LDS staging (4 KB LDS).
__global__ __launch_bounds__(256) void binscatter_k(
    const int* __restrict__ src, const int* __restrict__ dst,
    int* __restrict__ bcur, int* __restrict__ tmp, int E, int NB)
{
    __shared__ int hist[NBMAX];
    __shared__ int gb[NBMAX];
    const int t = threadIdx.x;
    for (int i = t; i < NB; i += 256) hist[i] = 0;
    __syncthreads();
    const int base = blockIdx.x * CHUNK;
    const int lim = min(CHUNK, E - base);
    int myb[16], myw[16], myr[16];
    int cnt = 0;
    for (int i = t; i < lim; i += 256) {
        int d = dst[base + i];
        int s_ = src[base + i];
        int b = d >> 8;
        myb[cnt] = b;
        myw[cnt] = (s_ << 8) | (d & 255);
        myr[cnt] = atomicAdd(&hist[b], 1);
        cnt++;
    }
    __syncthreads();
    for (int b = t; b < NB; b += 256)
        if (hist[b] > 0) gb[b] = atomicAdd(&bcur[b], hist[b]);
    __syncthreads();
    #pragma unroll 4
    for (int i = 0; i < cnt; i++)
        tmp[gb[myb[i]] + myr[i]] = myw[i];
}

// ============ csr: per bucket counting sort -> rowptr/rowend + adj ============
__global__ __launch_bounds__(256) void csr_k(
    const int* __restrict__ bcur, const int* __restrict__ tmp,
    int* __restrict__ rowptr, int* __restrict__ rowend,
    int* __restrict__ adj, int N)
{
    __shared__ int hist[256], pfx[256], cur[256], ssc[256];
    __shared__ int sadj[CAPC];
    const int b = blockIdx.x, t = threadIdx.x;
    const int lo = b * CAP;
    const int cnt = min(bcur[b] - lo, CAP);
    hist[t] = 0; cur[t] = 0;
    __syncthreads();
    for (int i = t; i < cnt; i += 256)
        atomicAdd(&hist[tmp[lo + i] & 255], 1);
    __syncthreads();
    int v = hist[t];
    ssc[t] = v;
    __syncthreads();
    for (int off = 1; off < 256; off <<= 1) {
        int a = (t >= off) ? ssc[t - off] : 0;
        __syncthreads();
        ssc[t] += a;
        __syncthreads();
    }
    pfx[t] = ssc[t] - v;
    const int node = b * 256 + t;
    if (node < N) {
        rowptr[node] = lo + pfx[t];
        rowend[node] = lo + pfx[t] + v;
    }
    __syncthreads();
    if (cnt <= CAPC) {
        for (int i = t; i < cnt; i += 256) {
            int w = tmp[lo + i];
            int d = w & 255;
            int p = pfx[d] + atomicAdd(&cur[d], 1);
            sadj[p] = w >> 8;
        }
        __syncthreads();
        for (int i = t; i < cnt; i += 256) adj[lo + i] = sadj[i];
    } else {
        for (int i = t; i < cnt; i += 256) {
            int w = tmp[lo + i];
            int d = w & 255;
            int p = pfx[d] + atomicAdd(&cur[d], 1);
            adj[lo + p] = w >> 8;
        }
    }
}

// ========== aggregation: z[n] = act(h[n]) + sum_m act(h[m]) ==========
// half-wave per node: lane carries feature pair via 4B load; unroll 16.
// AFFINE=1: act(v) = relu(v*sc+sh), sc/sh precomputed by bn_reduce_k.
template<int AFFINE>
__global__ __launch_bounds__(256) void aggregate_k(
    const bf16* __restrict__ h, const int* __restrict__ rowptr,
    const int* __restrict__ rowend, const int* __restrict__ adj,
    bf16* __restrict__ z, int N,
    const float* __restrict__ sc, const float* __restrict__ sh)
{
    const int lane = threadIdx.x & 31;
    const int n = blockIdx.x * 8 + (threadIdx.x >> 5);
    float sc0 = 0.f, sc1 = 0.f, sh0 = 0.f, sh1 = 0.f;
    if (AFFINE) {
        const int f0 = lane * 2;
        sc0 = sc[f0]; sc1 = sc[f0 + 1];
        sh0 = sh[f0]; sh1 = sh[f0 + 1];
    }
    if (n >= N) return;
    const unsigned* hp = (const unsigned*)h;   // bf16x2 words, row stride 32
    const int b = rowptr[n], e = rowend[n];

    unsigned u = hp[(size_t)n * 32 + lane];
    float a0 = bl(u), a1 = bh(u);
    if (AFFINE) {
        a0 = fmaxf(fmaf(a0, sc0, sh0), 0.f);
        a1 = fmaxf(fmaf(a1, sc1, sh1), 0.f);
    }
    float s0 = a0, s1 = a1;

    int i = b;
    for (; i + 16 <= e; i += 16) {
        int m[16];
        #pragma unroll
        for (int k = 0; k < 16; k++) m[k] = adj[i + k];
        unsigned w[16];
        #pragma unroll
        for (int k = 0; k < 16; k++) w[k] = hp[(size_t)m[k] * 32 + lane];
        #pragma unroll
        for (int k = 0; k < 16; k++) {
            float p0 = bl(w[k]), p1 = bh(w[k]);
            if (AFFINE) {
                p0 = fmaxf(fmaf(p0, sc0, sh0), 0.f);
                p1 = fmaxf(fmaf(p1, sc1, sh1), 0.f);
            }
            s0 += p0; s1 += p1;
        }
    }
    for (; i + 4 <= e; i += 4) {
        int m[4];
        #pragma unroll
        for (int k = 0; k < 4; k++) m[k] = adj[i + k];
        #pragma unroll
        for (int k = 0; k < 4; k++) {
            unsigned w = hp[(size_t)m[k] * 32 + lane];
            float p0 = bl(w), p1 = bh(w);
            if (AFFINE) {
                p0 = fmaxf(fmaf(p0, sc0, sh0), 0.f);
                p1 = fmaxf(fmaf(p1, sc1, sh1), 0.f);
            }
            s0 += p0; s1 += p1;
        }
    }
    for (; i < e; i++) {
        unsigned w = hp[(size_t)adj[i] * 32 + lane];
        float p0 = bl(w), p1 = bh(w);
        if (AFFINE) {
            p0 = fmaxf(fmaf(p0, sc0, sh0), 0.f);
            p1 = fmaxf(fmaf(p1, sc1, sh1), 0.f);
        }
        s0 += p0; s1 += p1;
    }
    ((unsigned*)z)[(size_t)n * 32 + lane] = pack2(s0, s1);
}

// ---------------- MFMA GEMM (bf16 in/out, f32 acc) ----------------
// C[N x 64] = act(A) @ W + bias.  MODE 0: act = id;  MODE 1: act = relu(A*sc+sh).
// 256 thr = 4 waves; 128 rows/block; per-block stats -> pstat (no atomics).
template<int MODE>
__global__ __launch_bounds__(256) void gemm64_k(
    const bf16* __restrict__ A,
    const float* __restrict__ scin, const float* __restrict__ shin,
    const float* __restrict__ W, const float* __restrict__ bias,
    bf16* __restrict__ out, float* __restrict__ pstat, int nrows)
{
    __shared__ bf16 sWt[64][72];     // transposed W (n-major)
    __shared__ float sSc[64], sSh[64], sB[64];
    __shared__ float sredS[64][17], sredQ[64][17];
    const int tid = threadIdx.x;

    if (tid < 64) {
        sB[tid] = bias[tid];
        if (MODE == 1) { sSc[tid] = scin[tid]; sSh[tid] = shin[tid]; }
    }
    for (int i = tid; i < 4096; i += 256) {
        int k = i >> 6, n = i & 63;
        sWt[n][k] = f2b(W[i]);
    }
    __syncthreads();

    const int wave = tid >> 6, lane = tid & 63;
    const int quad = lane >> 4, l16 = lane & 15;
    const int row0 = blockIdx.x * 128 + wave * 32;

    short8 a[2][2];
    #pragma unroll
    for (int rt = 0; rt < 2; rt++) {
        int r = row0 + rt * 16 + l16;
        int rr = min(r, nrows - 1);
        const bf16* arow = A + (size_t)rr * 64;
        a[rt][0] = *(const short8*)(arow + quad * 8);
        a[rt][1] = *(const short8*)(arow + 32 + quad * 8);
        if (MODE == 1) {
            #pragma unroll
            for (int j = 0; j < 8; j++) {
                int f0 = quad * 8 + j;
                a[rt][0][j] = f2bs(fmaxf(fmaf(bs2f(a[rt][0][j]), sSc[f0], sSh[f0]), 0.f));
                int f1 = 32 + f0;
                a[rt][1][j] = f2bs(fmaxf(fmaf(bs2f(a[rt][1][j]), sSc[f1], sSh[f1]), 0.f));
            }
        }
    }

    float psS[4], psQ[4];
    #pragma unroll
    for (int t = 0; t < 4; t++) { psS[t] = 0.f; psQ[t] = 0.f; }

    #pragma unroll
    for (int t = 0; t < 4; t++) {
        const int n = t * 16 + l16;
        short8 b0 = *(const short8*)&sWt[n][quad * 8];
        short8 b1 = *(const short8*)&sWt[n][32 + quad * 8];
        const float bn_ = sB[n];
        #pragma unroll
        for (int rt = 0; rt < 2; rt++) {
            f32x4 acc = {0.f, 0.f, 0.f, 0.f};
            acc = __builtin_amdgcn_mfma_f32_16x16x32_bf16(a[rt][0], b0, acc, 0, 0, 0);
            acc = __builtin_amdgcn_mfma_f32_16x16x32_bf16(a[rt][1], b1, acc, 0, 0, 0);
            #pragma unroll
            for (int reg = 0; reg < 4; reg++) {
                int gr = row0 + rt * 16 + quad * 4 + reg;
                if (gr < nrows) {
                    float v = acc[reg] + bn_;
                    out[(size_t)gr * 64 + n] = f2b(v);
                    psS[t] += v;
                    psQ[t] = fmaf(v, v, psQ[t]);
                }
            }
        }
    }

    #pragma unroll
    for (int t = 0; t < 4; t++) {
        sredS[t * 16 + l16][wave * 4 + quad] = psS[t];
        sredQ[t * 16 + l16][wave * 4 + quad] = psQ[t];
    }
    __syncthreads();
    if (tid < 128) {
        const int c = tid & 63;
        const float* p = (tid < 64) ? &sredS[c][0] : &sredQ[c][0];
        float s = 0.f;
        #pragma unroll
        for (int i = 0; i < 16; i++) s += p[i];
        pstat[(size_t)blockIdx.x * 128 + (tid < 64 ? c : 64 + c)] = s;
    }
}

// ---------------- reduce per-block stats -> scale/shift ----------------
// grid = 64 blocks (one per feature); thread t strides over gemm blocks.
__global__ __launch_bounds__(256) void bn_reduce_k(
    const float* __restrict__ pstat, int nblk,
    const float* __restrict__ g, const float* __restrict__ be, float invN,
    float* __restrict__ sc, float* __restrict__ sh)
{
    const int f = blockIdx.x;
    const int t = threadIdx.x;
    float S = 0.f, Q = 0.f;
    for (int b = t; b < nblk; b += 256) {
        S += pstat[(size_t)b * 128 + f];
        Q += pstat[(size_t)b * 128 + 64 + f];
    }
    __shared__ float rs[256], rq[256];
    rs[t] = S; rq[t] = Q;
    __syncthreads();
    for (int off = 128; off > 0; off >>= 1) {
        if (t < off) { rs[t] += rs[t + off]; rq[t] += rq[t + off]; }
        __syncthreads();
    }
    if (t == 0) {
        float m = rs[0] * invN;
        float v = rq[0] * invN - m * m;
        float s = g[f] * rsqrtf(v + BN_EPS);
        sc[f] = s;
        sh[f] = be[f] - m * s;
    }
}

// ---------------- pooled readout; h1/h2 affine+relu applied on the fly ----------------
__global__ __launch_bounds__(256) void pool_readout_k(
    const bf16* __restrict__ xb, const bf16* __restrict__ z0,
    const bf16* __restrict__ z1, const int* __restrict__ batch,
    const float* __restrict__ scA, const float* __restrict__ shA,
    const float* __restrict__ scB, const float* __restrict__ shB,
    const float* __restrict__ w0, const float* __restrict__ b0,
    const float* __restrict__ w1, const float* __restrict__ b1,
    const float* __restrict__ w2, const float* __restrict__ b2,
    float* __restrict__ out, int Nn)
{
    const int g = blockIdx.x;
    int lo = 0, hi = Nn;
    while (lo < hi) { int mid = (lo + hi) >> 1; if (batch[mid] < g) lo = mid + 1; else hi = mid; }
    const int start = lo;
    hi = Nn;
    while (lo < hi) { int mid = (lo + hi) >> 1; if (batch[mid] <= g) lo = mid + 1; else hi = mid; }
    const int end = lo;

    const int f = threadIdx.x & 63;
    const int w = threadIdx.x >> 6;
    const float sA = scA[f], tA = shA[f];
    const float sB = scB[f], tB = shB[f];

    float s0 = 0.f, s1 = 0.f, s2 = 0.f;
    for (int i = start + w; i < end; i += 4) {
        s0 += b2f(xb[(size_t)i * 64 + f]);
        s1 += fmaxf(fmaf(b2f(z0[(size_t)i * 64 + f]), sA, tA), 0.f);
        s2 += fmaxf(fmaf(b2f(z1[(size_t)i * 64 + f]), sB, tB), 0.f);
    }
    __shared__ float p[3][4][64];
    p[0][w][f] = s0; p[1][w][f] = s1; p[2][w][f] = s2;
    __syncthreads();
    if (threadIdx.x < 10) {
        const int c = threadIdx.x;
        float acc = b0[c] + b1[c] + b2[c];
        for (int k = 0; k < 64; k++) {
            float q0 = p[0][0][k] + p[0][1][k] + p[0][2][k] + p[0][3][k];
            float q1 = p[1][0][k] + p[1][1][k] + p[1][2][k] + p[1][3][k];
            float q2 = p[2][0][k] + p[2][1][k] + p[2][2][k] + p[2][3][k];
            acc = fmaf(q0, w0[k * 10 + c], acc);
            acc = fmaf(q1, w1[k * 10 + c], acc);
            acc = fmaf(q2, w2[k * 10 + c], acc);
        }
        out[(size_t)g * 10 + c] = acc;
    }
}

extern "C" void kernel_launch(void* const* d_in, const int* in_sizes, int n_in,
                              void* d_out, int out_size, void* d_ws, size_t ws_size,
                              hipStream_t stream)
{
    const float* x     = (const float*)d_in[0];
    const int*   edge  = (const int*)d_in[1];
    const int*   batch = (const int*)d_in[2];
    const int N = in_sizes[0] / 64;
    const int E = in_sizes[1] / 2;
    const int G = out_size / 10;
    const int* src = edge;
    const int* dst = edge + E;
    const int NB = (N + 255) / 256;

    const float* c_w1[2]  = {(const float*)d_in[3],  (const float*)d_in[11]};
    const float* c_b1[2]  = {(const float*)d_in[4],  (const float*)d_in[12]};
    const float* c_g1[2]  = {(const float*)d_in[5],  (const float*)d_in[13]};
    const float* c_be1[2] = {(const float*)d_in[6],  (const float*)d_in[14]};
    const float* c_w2[2]  = {(const float*)d_in[7],  (const float*)d_in[15]};
    const float* c_b2[2]  = {(const float*)d_in[8],  (const float*)d_in[16]};
    const float* bn_g[2]  = {(const float*)d_in[9],  (const float*)d_in[17]};
    const float* bn_b[2]  = {(const float*)d_in[10], (const float*)d_in[18]};
    const float* lw[3]    = {(const float*)d_in[19], (const float*)d_in[21], (const float*)d_in[23]};
    const float* lb[3]    = {(const float*)d_in[20], (const float*)d_in[22], (const float*)d_in[24]};

    float* out = (float*)d_out;
    const size_t nh = (size_t)N * 64;
    const int PG = (N + 127) / 128;   // gemm grid

    // workspace layout
    bf16*  zb    = (bf16*)d_ws;                // nh bf16 (L0 t/y buffer)
    bf16*  wb    = zb + nh;                    // nh bf16 (L1 t/y buffer)
    bf16*  xb    = wb + nh;                    // nh bf16
    float* scsh  = (float*)(xb + nh);          // 8 x 64
    float* pstat = scsh + 512;                 // PG x 128
    int*   rowptr = (int*)(pstat + (size_t)PG * 128);  // N
    int*   rowend = rowptr + N;                // N
    int*   adj    = rowend + N;                // NB*CAP
    int*   tmp    = adj + (size_t)NB * CAP;    // NB*CAP
    int*   bcur   = tmp + (size_t)NB * CAP;    // NB

    float* sc0 = scsh;       float* sh0 = scsh + 64;
    float* scA = scsh + 128; float* shA = scsh + 192;
    float* sc2 = scsh + 256; float* sh2 = scsh + 320;
    float* scB = scsh + 384; float* shB = scsh + 448;

    const float invN = 1.0f / (float)N;
    const int binGrid  = (E + CHUNK - 1) / CHUNK;
    const int aggGrid  = (N + 7) / 8;
    const int ewGrid   = (int)((nh / 4 + 255) / 256);

    // ---- init+cast, CSR build (fixed-stride buckets; no histogram pre-pass) ----
    initcast_k<<<ewGrid, 256, 0, stream>>>(x, xb, (int)(nh / 4), bcur, NB);
    binscatter_k<<<binGrid, 256, 0, stream>>>(src, dst, bcur, tmp, E, NB);
    csr_k<<<NB, 256, 0, stream>>>(bcur, tmp, rowptr, rowend, adj, N);

    // ---- layer 0 ----
    aggregate_k<0><<<aggGrid, 256, 0, stream>>>(xb, rowptr, rowend, adj, zb, N,
                                                nullptr, nullptr);
    gemm64_k<0><<<PG, 256, 0, stream>>>(zb, nullptr, nullptr,
                                        c_w1[0], c_b1[0], zb, pstat, N);
    bn_reduce_k<<<64, 256, 0, stream>>>(pstat, PG, c_g1[0], c_be1[0], invN, sc0, sh0);
    gemm64_k<1><<<PG, 256, 0, stream>>>(zb, sc0, sh0,
                                        c_w2[0], c_b2[0], zb, pstat, N);
    bn_reduce_k<<<64, 256, 0, stream>>>(pstat, PG, bn_g[0], bn_b[0], invN, scA, shA);

    // ---- layer 1 (h1 = relu(affine(y0)) applied inside aggregate) ----
    aggregate_k<1><<<aggGrid, 256, 0, stream>>>(zb, rowptr, rowend, adj, wb, N,
                                                scA, shA);
    gemm64_k<0><<<PG, 256, 0, stream>>>(wb, nullptr, nullptr,
                                        c_w1[1], c_b1[1], wb, pstat, N);
    bn_reduce_k<<<64, 256, 0, stream>>>(pstat, PG, c_g1[1], c_be1[1], invN, sc2, sh2);
    gemm64_k<1><<<PG, 256, 0, stream>>>(wb, sc2, sh2,
                                        c_w2[1], c_b2[1], wb, pstat, N);
    bn_reduce_k<<<64, 256, 0, stream>>>(pstat, PG, bn_g[1], bn_b[1], invN, scB, shB);

    // ---- pooled readout (h1/h2 affine+relu fused) ----
    pool_readout_k<<<G, 256, 0, stream>>>(xb, zb, wb, batch,
                                          scA, shA, scB, shB,
                                          lw[0], lb[0], lw[1], lb[1], lw[2], lb[2],
                                          out, N);
}

// Round 15
// 309.369 us; speedup vs baseline: 1.4908x; 1.0178x over previous
//
#include <hip/hip_runtime.h>
#include <hip/hip_bf16.h>

#define BN_EPS 1e-5f
#define NBMAX 512      // max buckets (N/256)
#define CHUNK 4096     // edges per binning block
#define CAP   5120     // fixed per-bucket capacity (mean 4096 + 16 sigma)
#define CAPC  6144     // per-bucket LDS staging capacity

typedef __hip_bfloat16 bf16;
typedef __attribute__((ext_vector_type(8))) short short8;
typedef __attribute__((ext_vector_type(4))) float f32x4;

__device__ __forceinline__ float b2f(bf16 v) { return __bfloat162float(v); }
__device__ __forceinline__ bf16 f2b(float v) { return __float2bfloat16(v); }
__device__ __forceinline__ float bl(unsigned u) { return __uint_as_float(u << 16); }
__device__ __forceinline__ float bh(unsigned u) { return __uint_as_float(u & 0xffff0000u); }
__device__ __forceinline__ unsigned pack2(float x, float y) {
    union { bf16 b[2]; unsigned u; } p;
    p.b[0] = f2b(x); p.b[1] = f2b(y);
    return p.u;
}
__device__ __forceinline__ float bs2f(short s) {
    return __uint_as_float(((unsigned)(unsigned short)s) << 16);
}
__device__ __forceinline__ short f2bs(float v) {
    bf16 b = f2b(v);
    return *reinterpret_cast<short*>(&b);
}

// ============ init bcur (fixed-stride bases) + cast x -> bf16 ============
__global__ __launch_bounds__(256) void initcast_k(
    const float* __restrict__ in, bf16* __restrict__ out, int total4,
    int* __restrict__ bcur, int NB)
{
    if (blockIdx.x == 0) {
        for (int i = threadIdx.x; i < NB; i += 256) bcur[i] = i * CAP;
    }
    int i = blockIdx.x * 256 + threadIdx.x;
    if (i >= total4) return;
    float4 v = ((const float4*)in)[i];
    union { ushort4 u; bf16 b[4]; } p;
    p.b[0] = f2b(v.x); p.b[1] = f2b(v.y); p.b[2] = f2b(v.z); p.b[3] = f2b(v.w);
    ((ushort4*)out)[i] = p.u;
}

// ============ binscatter: group edges by bucket in LDS, write coalesced runs ====
__global__ __launch_bounds__(256) void binscatter_k(
    const int* __restrict__ src, const int* __restrict__ dst,
    int* __restrict__ bcur, int* __restrict__ tmp, int E, int NB)
{
    __shared__ int hist[NBMAX];
    __shared__ int loff[NBMAX];
    __shared__ int gb[NBMAX];
    __shared__ int lcur[NBMAX];
    __shared__ int staged[CHUNK];
    __shared__ unsigned short sb[CHUNK];
    __shared__ int ssc[256];
    const int t = threadIdx.x;
    for (int i = t; i < NB; i += 256) { hist[i] = 0; lcur[i] = 0; }
    __syncthreads();
    const int base = blockIdx.x * CHUNK;
    const int lim = min(CHUNK, E - base);
    int myb[16], myw[16];
    int cnt = 0;
    for (int i = t; i < lim; i += 256) {
        int d = dst[base + i];
        int s_ = src[base + i];
        int b = d >> 8;
        myb[cnt] = b;
        myw[cnt] = (s_ << 8) | (d & 255);
        cnt++;
        atomicAdd(&hist[b], 1);
    }
    __syncthreads();
    int v0 = (2 * t     < NB) ? hist[2 * t]     : 0;
    int v1 = (2 * t + 1 < NB) ? hist[2 * t + 1] : 0;
    ssc[t] = v0 + v1;
    __syncthreads();
    for (int off = 1; off < 256; off <<= 1) {
        int a = (t >= off) ? ssc[t - off] : 0;
        __syncthreads();
        ssc[t] += a;
        __syncthreads();
    }
    int excl = ssc[t] - (v0 + v1);
    if (2 * t < NB)     loff[2 * t] = excl;
    if (2 * t + 1 < NB) loff[2 * t + 1] = excl + v0;
    __syncthreads();
    for (int b = t; b < NB; b += 256)
        if (hist[b] > 0) gb[b] = atomicAdd(&bcur[b], hist[b]);
    for (int i = 0; i < cnt; i++) {
        int b = myb[i];
        int p = loff[b] + atomicAdd(&lcur[b], 1);
        staged[p] = myw[i];
        sb[p] = (unsigned short)b;
    }
    __syncthreads();
    for (int i = t; i < lim; i += 256) {
        int b = sb[i];
        tmp[gb[b] + (i - loff[b])] = staged[i];
    }
}

// ============ csr: per bucket counting sort -> rowptr/rowend + adj ============
__global__ __launch_bounds__(256) void csr_k(
    const int* __restrict__ bcur, const int* __restrict__ tmp,
    int* __restrict__ rowptr, int* __restrict__ rowend,
    int* __restrict__ adj, int N)
{
    __shared__ int hist[256], pfx[256], cur[256], ssc[256];
    __shared__ int sadj[CAPC];
    const int b = blockIdx.x, t = threadIdx.x;
    const int lo = b * CAP;
    const int cnt = min(bcur[b] - lo, CAP);
    hist[t] = 0; cur[t] = 0;
    __syncthreads();
    for (int i = t; i < cnt; i += 256)
        atomicAdd(&hist[tmp[lo + i] & 255], 1);
    __syncthreads();
    int v = hist[t];
    ssc[t] = v;
    __syncthreads();
    for (int off = 1; off < 256; off <<= 1) {
        int a = (t >= off) ? ssc[t - off] : 0;
        __syncthreads();
        ssc[t] += a;
        __syncthreads();
    }
    pfx[t] = ssc[t] - v;
    const int node = b * 256 + t;
    if (node < N) {
        rowptr[node] = lo + pfx[t];
        rowend[node] = lo + pfx[t] + v;
    }
    __syncthreads();
    if (cnt <= CAPC) {
        for (int i = t; i < cnt; i += 256) {
            int w = tmp[lo + i];
            int d = w & 255;
            int p = pfx[d] + atomicAdd(&cur[d], 1);
            sadj[p] = w >> 8;
        }
        __syncthreads();
        for (int i = t; i < cnt; i += 256) adj[lo + i] = sadj[i];
    } else {
        for (int i = t; i < cnt; i += 256) {
            int w = tmp[lo + i];
            int d = w & 255;
            int p = pfx[d] + atomicAdd(&cur[d], 1);
            adj[lo + p] = w >> 8;
        }
    }
}

// ========== aggregation: z[n] = act(h[n]) + sum_m act(h[m]) ==========
// half-wave per node: lane carries feature pair via 4B load; unroll 16.
// AFFINE=1: act(v) = relu(v*sc+sh), sc/sh precomputed by bn_reduce_k.
template<int AFFINE>
__global__ __launch_bounds__(256) void aggregate_k(
    const bf16* __restrict__ h, const int* __restrict__ rowptr,
    const int* __restrict__ rowend, const int* __restrict__ adj,
    bf16* __restrict__ z, int N,
    const float* __restrict__ sc, const float* __restrict__ sh)
{
    const int lane = threadIdx.x & 31;
    const int n = blockIdx.x * 8 + (threadIdx.x >> 5);
    float sc0 = 0.f, sc1 = 0.f, sh0 = 0.f, sh1 = 0.f;
    if (AFFINE) {
        const int f0 = lane * 2;
        sc0 = sc[f0]; sc1 = sc[f0 + 1];
        sh0 = sh[f0]; sh1 = sh[f0 + 1];
    }
    if (n >= N) return;
    const unsigned* hp = (const unsigned*)h;   // bf16x2 words, row stride 32
    const int b = rowptr[n], e = rowend[n];

    unsigned u = hp[(size_t)n * 32 + lane];
    float a0 = bl(u), a1 = bh(u);
    if (AFFINE) {
        a0 = fmaxf(fmaf(a0, sc0, sh0), 0.f);
        a1 = fmaxf(fmaf(a1, sc1, sh1), 0.f);
    }
    float s0 = a0, s1 = a1;

    int i = b;
    for (; i + 16 <= e; i += 16) {
        int m[16];
        #pragma unroll
        for (int k = 0; k < 16; k++) m[k] = adj[i + k];
        unsigned w[16];
        #pragma unroll
        for (int k = 0; k < 16; k++) w[k] = hp[(size_t)m[k] * 32 + lane];
        #pragma unroll
        for (int k = 0; k < 16; k++) {
            float p0 = bl(w[k]), p1 = bh(w[k]);
            if (AFFINE) {
                p0 = fmaxf(fmaf(p0, sc0, sh0), 0.f);
                p1 = fmaxf(fmaf(p1, sc1, sh1), 0.f);
            }
            s0 += p0; s1 += p1;
        }
    }
    for (; i + 4 <= e; i += 4) {
        int m[4];
        #pragma unroll
        for (int k = 0; k < 4; k++) m[k] = adj[i + k];
        #pragma unroll
        for (int k = 0; k < 4; k++) {
            unsigned w = hp[(size_t)m[k] * 32 + lane];
            float p0 = bl(w), p1 = bh(w);
            if (AFFINE) {
                p0 = fmaxf(fmaf(p0, sc0, sh0), 0.f);
                p1 = fmaxf(fmaf(p1, sc1, sh1), 0.f);
            }
            s0 += p0; s1 += p1;
        }
    }
    for (; i < e; i++) {
        unsigned w = hp[(size_t)adj[i] * 32 + lane];
        float p0 = bl(w), p1 = bh(w);
        if (AFFINE) {
            p0 = fmaxf(fmaf(p0, sc0, sh0), 0.f);
            p1 = fmaxf(fmaf(p1, sc1, sh1), 0.f);
        }
        s0 += p0; s1 += p1;
    }
    ((unsigned*)z)[(size_t)n * 32 + lane] = pack2(s0, s1);
}

// ---------------- MFMA GEMM (bf16 in/out, f32 acc) ----------------
// C[N x 64] = act(A) @ W + bias.  MODE 0: act = id;  MODE 1: act = relu(A*sc+sh).
// 256 thr = 4 waves; 128 rows/block; per-block stats -> pstat (no atomics).
// C-tile staged in LDS (136B row stride) -> coalesced ushort4 stores (512B/wave-instr).
// In-place safe: all A loads complete before the barrier; stores after.
template<int MODE>
__global__ __launch_bounds__(256) void gemm64_k(
    const bf16* __restrict__ A,
    const float* __restrict__ scin, const float* __restrict__ shin,
    const float* __restrict__ W, const float* __restrict__ bias,
    bf16* __restrict__ out, float* __restrict__ pstat, int nrows)
{
    __shared__ bf16 sWt[64][72];     // transposed W (n-major)
    __shared__ bf16 sC[128][68];     // C tile; 136B rows: 8B-aligned, 2-way bank alias
    __shared__ float sSc[64], sSh[64], sB[64];
    __shared__ float sredS[64][17], sredQ[64][17];
    const int tid = threadIdx.x;

    if (tid < 64) {
        sB[tid] = bias[tid];
        if (MODE == 1) { sSc[tid] = scin[tid]; sSh[tid] = shin[tid]; }
    }
    for (int i = tid; i < 4096; i += 256) {
        int k = i >> 6, n = i & 63;
        sWt[n][k] = f2b(W[i]);
    }
    __syncthreads();

    const int wave = tid >> 6, lane = tid & 63;
    const int quad = lane >> 4, l16 = lane & 15;
    const int row0 = blockIdx.x * 128 + wave * 32;

    short8 a[2][2];
    #pragma unroll
    for (int rt = 0; rt < 2; rt++) {
        int r = row0 + rt * 16 + l16;
        int rr = min(r, nrows - 1);
        const bf16* arow = A + (size_t)rr * 64;
        a[rt][0] = *(const short8*)(arow + quad * 8);
        a[rt][1] = *(const short8*)(arow + 32 + quad * 8);
        if (MODE == 1) {
            #pragma unroll
            for (int j = 0; j < 8; j++) {
                int f0 = quad * 8 + j;
                a[rt][0][j] = f2bs(fmaxf(fmaf(bs2f(a[rt][0][j]), sSc[f0], sSh[f0]), 0.f));
                int f1 = 32 + f0;
                a[rt][1][j] = f2bs(fmaxf(fmaf(bs2f(a[rt][1][j]), sSc[f1], sSh[f1]), 0.f));
            }
        }
    }

    float psS[4], psQ[4];
    #pragma unroll
    for (int t = 0; t < 4; t++) { psS[t] = 0.f; psQ[t] = 0.f; }

    #pragma unroll
    for (int t = 0; t < 4; t++) {
        const int n = t * 16 + l16;
        short8 b0 = *(const short8*)&sWt[n][quad * 8];
        short8 b1 = *(const short8*)&sWt[n][32 + quad * 8];
        const float bn_ = sB[n];
        #pragma unroll
        for (int rt = 0; rt < 2; rt++) {
            f32x4 acc = {0.f, 0.f, 0.f, 0.f};
            acc = __builtin_amdgcn_mfma_f32_16x16x32_bf16(a[rt][0], b0, acc, 0, 0, 0);
            acc = __builtin_amdgcn_mfma_f32_16x16x32_bf16(a[rt][1], b1, acc, 0, 0, 0);
            #pragma unroll
            for (int reg = 0; reg < 4; reg++) {
                const int lr = wave * 32 + rt * 16 + quad * 4 + reg;  // local row
                float v = acc[reg] + bn_;
                sC[lr][n] = f2b(v);
                if (row0 + rt * 16 + quad * 4 + reg < nrows) {
                    psS[t] += v;
                    psQ[t] = fmaf(v, v, psQ[t]);
                }
            }
        }
    }

    #pragma unroll
    for (int t = 0; t < 4; t++) {
        sredS[t * 16 + l16][wave * 4 + quad] = psS[t];
        sredQ[t * 16 + l16][wave * 4 + quad] = psQ[t];
    }
    __syncthreads();

    // coalesced C-tile writeout: 2048 ushort4 chunks (128 rows x 16)
    const int gbase = blockIdx.x * 128;
    #pragma unroll
    for (int it = 0; it < 8; it++) {
        int idx = it * 256 + tid;
        int r = idx >> 4, c4 = idx & 15;
        if (gbase + r < nrows) {
            ushort4 v = *(const ushort4*)&sC[r][c4 * 4];
            *(ushort4*)(out + (size_t)(gbase + r) * 64 + c4 * 4) = v;
        }
    }

    if (tid < 128) {
        const int c = tid & 63;
        const float* p = (tid < 64) ? &sredS[c][0] : &sredQ[c][0];
        float s = 0.f;
        #pragma unroll
        for (int i = 0; i < 16; i++) s += p[i];
        pstat[(size_t)blockIdx.x * 128 + (tid < 64 ? c : 64 + c)] = s;
    }
}

// ---------------- reduce per-block stats -> scale/shift ----------------
// grid = 64 blocks (one per feature); thread t strides over gemm blocks.
__global__ __launch_bounds__(256) void bn_reduce_k(
    const float* __restrict__ pstat, int nblk,
    const float* __restrict__ g, const float* __restrict__ be, float invN,
    float* __restrict__ sc, float* __restrict__ sh)
{
    const int f = blockIdx.x;
    const int t = threadIdx.x;
    float S = 0.f, Q = 0.f;
    for (int b = t; b < nblk; b += 256) {
        S += pstat[(size_t)b * 128 + f];
        Q += pstat[(size_t)b * 128 + 64 + f];
    }
    __shared__ float rs[256], rq[256];
    rs[t] = S; rq[t] = Q;
    __syncthreads();
    for (int off = 128; off > 0; off >>= 1) {
        if (t < off) { rs[t] += rs[t + off]; rq[t] += rq[t + off]; }
        __syncthreads();
    }
    if (t == 0) {
        float m = rs[0] * invN;
        float v = rq[0] * invN - m * m;
        float s = g[f] * rsqrtf(v + BN_EPS);
        sc[f] = s;
        sh[f] = be[f] - m * s;
    }
}

// ---------------- pooled readout; h1/h2 affine+relu applied on the fly ----------------
__global__ __launch_bounds__(256) void pool_readout_k(
    const bf16* __restrict__ xb, const bf16* __restrict__ z0,
    const bf16* __restrict__ z1, const int* __restrict__ batch,
    const float* __restrict__ scA, const float* __restrict__ shA,
    const float* __restrict__ scB, const float* __restrict__ shB,
    const float* __restrict__ w0, const float* __restrict__ b0,
    const float* __restrict__ w1, const float* __restrict__ b1,
    const float* __restrict__ w2, const float* __restrict__ b2,
    float* __restrict__ out, int Nn)
{
    const int g = blockIdx.x;
    int lo = 0, hi = Nn;
    while (lo < hi) { int mid = (lo + hi) >> 1; if (batch[mid] < g) lo = mid + 1; else hi = mid; }
    const int start = lo;
    hi = Nn;
    while (lo < hi) { int mid = (lo + hi) >> 1; if (batch[mid] <= g) lo = mid + 1; else hi = mid; }
    const int end = lo;

    const int f = threadIdx.x & 63;
    const int w = threadIdx.x >> 6;
    const float sA = scA[f], tA = shA[f];
    const float sB = scB[f], tB = shB[f];

    float s0 = 0.f, s1 = 0.f, s2 = 0.f;
    for (int i = start + w; i < end; i += 4) {
        s0 += b2f(xb[(size_t)i * 64 + f]);
        s1 += fmaxf(fmaf(b2f(z0[(size_t)i * 64 + f]), sA, tA), 0.f);
        s2 += fmaxf(fmaf(b2f(z1[(size_t)i * 64 + f]), sB, tB), 0.f);
    }
    __shared__ float p[3][4][64];
    p[0][w][f] = s0; p[1][w][f] = s1; p[2][w][f] = s2;
    __syncthreads();
    if (threadIdx.x < 10) {
        const int c = threadIdx.x;
        float acc = b0[c] + b1[c] + b2[c];
        for (int k = 0; k < 64; k++) {
            float q0 = p[0][0][k] + p[0][1][k] + p[0][2][k] + p[0][3][k];
            float q1 = p[1][0][k] + p[1][1][k] + p[1][2][k] + p[1][3][k];
            float q2 = p[2][0][k] + p[2][1][k] + p[2][2][k] + p[2][3][k];
            acc = fmaf(q0, w0[k * 10 + c], acc);
            acc = fmaf(q1, w1[k * 10 + c], acc);
            acc = fmaf(q2, w2[k * 10 + c], acc);
        }
        out[(size_t)g * 10 + c] = acc;
    }
}

extern "C" void kernel_launch(void* const* d_in, const int* in_sizes, int n_in,
                              void* d_out, int out_size, void* d_ws, size_t ws_size,
                              hipStream_t stream)
{
    const float* x     = (const float*)d_in[0];
    const int*   edge  = (const int*)d_in[1];
    const int*   batch = (const int*)d_in[2];
    const int N = in_sizes[0] / 64;
    const int E = in_sizes[1] / 2;
    const int G = out_size / 10;
    const int* src = edge;
    const int* dst = edge + E;
    const int NB = (N + 255) / 256;

    const float* c_w1[2]  = {(const float*)d_in[3],  (const float*)d_in[11]};
    const float* c_b1[2]  = {(const float*)d_in[4],  (const float*)d_in[12]};
    const float* c_g1[2]  = {(const float*)d_in[5],  (const float*)d_in[13]};
    const float* c_be1[2] = {(const float*)d_in[6],  (const float*)d_in[14]};
    const float* c_w2[2]  = {(const float*)d_in[7],  (const float*)d_in[15]};
    const float* c_b2[2]  = {(const float*)d_in[8],  (const float*)d_in[16]};
    const float* bn_g[2]  = {(const float*)d_in[9],  (const float*)d_in[17]};
    const float* bn_b[2]  = {(const float*)d_in[10], (const float*)d_in[18]};
    const float* lw[3]    = {(const float*)d_in[19], (const float*)d_in[21], (const float*)d_in[23]};
    const float* lb[3]    = {(const float*)d_in[20], (const float*)d_in[22], (const float*)d_in[24]};

    float* out = (float*)d_out;
    const size_t nh = (size_t)N * 64;
    const int PG = (N + 127) / 128;   // gemm grid

    // workspace layout
    bf16*  zb    = (bf16*)d_ws;                // nh bf16 (L0 t/y buffer)
    bf16*  wb    = zb + nh;                    // nh bf16 (L1 t/y buffer)
    bf16*  xb    = wb + nh;                    // nh bf16
    float* scsh  = (float*)(xb + nh);          // 8 x 64
    float* pstat = scsh + 512;                 // PG x 128
    int*   rowptr = (int*)(pstat + (size_t)PG * 128);  // N
    int*   rowend = rowptr + N;                // N
    int*   adj    = rowend + N;                // NB*CAP
    int*   tmp    = adj + (size_t)NB * CAP;    // NB*CAP
    int*   bcur   = tmp + (size_t)NB * CAP;    // NB

    float* sc0 = scsh;       float* sh0 = scsh + 64;
    float* scA = scsh + 128; float* shA = scsh + 192;
    float* sc2 = scsh + 256; float* sh2 = scsh + 320;
    float* scB = scsh + 384; float* shB = scsh + 448;

    const float invN = 1.0f / (float)N;
    const int binGrid  = (E + CHUNK - 1) / CHUNK;
    const int aggGrid  = (N + 7) / 8;
    const int ewGrid   = (int)((nh / 4 + 255) / 256);

    // ---- init+cast, CSR build (fixed-stride buckets) ----
    initcast_k<<<ewGrid, 256, 0, stream>>>(x, xb, (int)(nh / 4), bcur, NB);
    binscatter_k<<<binGrid, 256, 0, stream>>>(src, dst, bcur, tmp, E, NB);
    csr_k<<<NB, 256, 0, stream>>>(bcur, tmp, rowptr, rowend, adj, N);

    // ---- layer 0 ----
    aggregate_k<0><<<aggGrid, 256, 0, stream>>>(xb, rowptr, rowend, adj, zb, N,
                                                nullptr, nullptr);
    gemm64_k<0><<<PG, 256, 0, stream>>>(zb, nullptr, nullptr,
                                        c_w1[0], c_b1[0], zb, pstat, N);
    bn_reduce_k<<<64, 256, 0, stream>>>(pstat, PG, c_g1[0], c_be1[0], invN, sc0, sh0);
    gemm64_k<1><<<PG, 256, 0, stream>>>(zb, sc0, sh0,
                                        c_w2[0], c_b2[0], zb, pstat, N);
    bn_reduce_k<<<64, 256, 0, stream>>>(pstat, PG, bn_g[0], bn_b[0], invN, scA, shA);

    // ---- layer 1 (h1 = relu(affine(y0)) applied inside aggregate) ----
    aggregate_k<1><<<aggGrid, 256, 0, stream>>>(zb, rowptr, rowend, adj, wb, N,
                                                scA, shA);
    gemm64_k<0><<<PG, 256, 0, stream>>>(wb, nullptr, nullptr,
                                        c_w1[1], c_b1[1], wb, pstat, N);
    bn_reduce_k<<<64, 256, 0, stream>>>(pstat, PG, c_g1[1], c_be1[1], invN, sc2, sh2);
    gemm64_k<1><<<PG, 256, 0, stream>>>(wb, sc2, sh2,
                                        c_w2[1], c_b2[1], wb, pstat, N);
    bn_reduce_k<<<64, 256, 0, stream>>>(pstat, PG, bn_g[1], bn_b[1], invN, scB, shB);

    // ---- pooled readout (h1/h2 affine+relu fused) ----
    pool_readout_k<<<G, 256, 0, stream>>>(xb, zb, wb, batch,
                                          scA, shA, scB, shB,
                                          lw[0], lb[0], lw[1], lb[1], lw[2], lb[2],
                                          out, N);
}